// Round 3
// baseline (537.197 us; speedup 1.0000x reference)
//
#include <hip/hip_runtime.h>

// ForceGrid: scatter-add 10M weighted particles into a 256^3 float grid.
//
// Numerics: the JAX/XLA reference constant-folds dx = fl32(20/255) and its
// algebraic simplifier rewrites the division into multiplication by the
// fp32 reciprocal, which folds to EXACTLY 12.75f. Evidence: fp32-division
// and f64 index paths both differ from ref by the identical absmax
// (0.99609375) -> differing set is precision-independent on our side, i.e.
// the ref itself carries the fp32-multiply rounding. So replicate:
//   s  = fl32(p + 10.0f)
//   fi = fl32(s * 12.75f)          // multiply, NOT division
//   i  = (int32)fl32(fi + 0.5f)    // C trunc-toward-zero
//   in-grid iff all three i in [0,256); flat = (ix*256 + iy)*256 + iz
// fp contract(off) is required: -ffp-contract=fast would fuse s*12.75f+0.5f
// into an FMA and change the trunc decisions again.

constexpr int GRID_N = 256;

__global__ __launch_bounds__(256) void forcegrid_scatter(
    const float* __restrict__ pos,   // [N,3] AoS
    const float* __restrict__ wgt,   // [N]
    float* __restrict__ grid,        // [256^3], pre-zeroed
    int n_particles)
{
#pragma clang fp contract(off)
    int t = blockIdx.x * blockDim.x + threadIdx.x;   // one thread = 4 particles
    long long base = (long long)t * 4;
    if (base >= n_particles) return;

    // 4 particles = 12 floats of position -> three coalesced float4 loads.
    const float4* p4 = (const float4*)pos;
    float4 a = p4[(size_t)t * 3 + 0];
    float4 b = p4[(size_t)t * 3 + 1];
    float4 c = p4[(size_t)t * 3 + 2];
    float4 w = ((const float4*)wgt)[t];

    float px[4] = {a.x, a.w, b.z, c.y};
    float py[4] = {a.y, b.x, b.w, c.z};
    float pz[4] = {a.z, b.y, c.x, c.w};
    float ww[4] = {w.x, w.y, w.z, w.w};

#pragma unroll
    for (int k = 0; k < 4; ++k) {
        if (base + k >= n_particles) break;
        float sx = px[k] + 10.0f;
        float sy = py[k] + 10.0f;
        float sz = pz[k] + 10.0f;
        float fix = sx * 12.75f;     // == fl32(1/fl32(20/255)) exactly
        float fiy = sy * 12.75f;
        float fiz = sz * 12.75f;
        int ix = (int)(fix + 0.5f);  // trunc-toward-zero, separate add (no FMA)
        int iy = (int)(fiy + 0.5f);
        int iz = (int)(fiz + 0.5f);

        bool in = (ix >= 0) & (ix < GRID_N) &
                  (iy >= 0) & (iy < GRID_N) &
                  (iz >= 0) & (iz < GRID_N);
        if (in) {
            int flat = (ix << 16) | (iy << 8) | iz;   // (ix*256 + iy)*256 + iz
            atomicAdd(&grid[flat], ww[k]);
        }
    }
}

extern "C" void kernel_launch(void* const* d_in, const int* in_sizes, int n_in,
                              void* d_out, int out_size, void* d_ws, size_t ws_size,
                              hipStream_t stream)
{
    const float* pos = (const float*)d_in[0];   // [N,3]
    const float* wgt = (const float*)d_in[1];   // [N]
    float* grid = (float*)d_out;                // [256^3]

    int n_particles = in_sizes[0] / 3;          // 10,000,000

    // d_out is poisoned to 0xAA before every timed call — zero it on-stream.
    hipMemsetAsync(grid, 0, (size_t)out_size * sizeof(float), stream);

    int groups = (n_particles + 3) / 4;         // particles per thread = 4
    int blocks = (groups + 255) / 256;
    forcegrid_scatter<<<blocks, 256, 0, stream>>>(pos, wgt, grid, n_particles);
}

// Round 4
// 454.175 us; speedup vs baseline: 1.1828x; 1.1828x over previous
//
#include <hip/hip_runtime.h>
#include <stdint.h>

// ForceGrid: 10M weighted particles -> 256^3 float grid.
//
// Round-3 finding: single-pass global fp atomics wall at ~1 atomic/cycle/XCD
// (19.8G/s -> 379us). This version removes ALL global atomics via a
// counting-sort by 4096 grid bins (bin = flat>>12, 4096 cells = 16KB LDS),
// then per-bin LDS accumulation + plain coalesced stores (no d_out memset).
//
// Numerics (bit-exact vs the XLA-folded reference; DO NOT change):
//   fi = fl32((p + 10.0f) * 12.75f)   // 12.75f == fl32(1/fl32(20/255))
//   i  = (int32)fl32(fi + 0.5f)       // trunc toward zero, NO FMA contraction

constexpr int GRID_N = 256;
constexpr int NBINS  = 4096;   // bin = flat >> 12 ; cell_local = flat & 4095
constexpr int NB     = 512;    // blocks for hist/scatter passes
constexpr int BT     = 256;    // threads per block

__device__ __forceinline__ int particle_flat(float px, float py, float pz) {
#pragma clang fp contract(off)
    float fix = (px + 10.0f) * 12.75f;
    float fiy = (py + 10.0f) * 12.75f;
    float fiz = (pz + 10.0f) * 12.75f;
    int ix = (int)(fix + 0.5f);
    int iy = (int)(fiy + 0.5f);
    int iz = (int)(fiz + 0.5f);
    bool in = (ix >= 0) & (ix < GRID_N) &
              (iy >= 0) & (iy < GRID_N) &
              (iz >= 0) & (iz < GRID_N);
    return in ? ((ix << 16) | (iy << 8) | iz) : -1;
}

// ---- K1: per-block bin histogram (LDS atomics), hist[NB][NBINS] -------------
__global__ __launch_bounds__(BT) void k1_hist(const float* __restrict__ pos,
                                              uint32_t* __restrict__ hist,
                                              int n)
{
    __shared__ uint32_t h[NBINS];
    for (int i = threadIdx.x; i < NBINS; i += BT) h[i] = 0;
    __syncthreads();

    const float4* p4 = (const float4*)pos;
    int ngroups = n >> 2;
    int G = gridDim.x * BT;
    for (int g = blockIdx.x * BT + threadIdx.x; g < ngroups; g += G) {
        float4 a = p4[(size_t)g * 3 + 0];
        float4 b = p4[(size_t)g * 3 + 1];
        float4 c = p4[(size_t)g * 3 + 2];
        int f0 = particle_flat(a.x, a.y, a.z);
        int f1 = particle_flat(a.w, b.x, b.y);
        int f2 = particle_flat(b.z, b.w, c.x);
        int f3 = particle_flat(c.y, c.z, c.w);
        if (f0 >= 0) atomicAdd(&h[f0 >> 12], 1u);
        if (f1 >= 0) atomicAdd(&h[f1 >> 12], 1u);
        if (f2 >= 0) atomicAdd(&h[f2 >> 12], 1u);
        if (f3 >= 0) atomicAdd(&h[f3 >> 12], 1u);
    }
    // tail (n % 4) particles, counted by block 0 only
    if (blockIdx.x == 0 && threadIdx.x == 0) {
        for (int p = n & ~3; p < n; ++p) {
            int f = particle_flat(pos[3 * p], pos[3 * p + 1], pos[3 * p + 2]);
            if (f >= 0) atomicAdd(&h[f >> 12], 1u);
        }
    }
    __syncthreads();
    uint32_t* out = hist + (size_t)blockIdx.x * NBINS;
    for (int i = threadIdx.x; i < NBINS; i += BT) out[i] = h[i];
}

// ---- K2a: per-bin scan across blocks (coalesced columns) --------------------
__global__ __launch_bounds__(128) void k2a_colscan(const uint32_t* __restrict__ hist,
                                                   uint32_t* __restrict__ offs,
                                                   uint32_t* __restrict__ totals)
{
    int b = blockIdx.x * 128 + threadIdx.x;   // 32 blocks x 128 = 4096 bins
    uint32_t run = 0;
#pragma unroll 8
    for (int blk = 0; blk < NB; ++blk) {
        uint32_t v = hist[(size_t)blk * NBINS + b];
        offs[(size_t)blk * NBINS + b] = run;
        run += v;
    }
    totals[b] = run;
}

// ---- K2b: exclusive scan of 4096 bin totals -> base[NBINS+1] ----------------
__global__ __launch_bounds__(256) void k2b_scan(const uint32_t* __restrict__ totals,
                                                uint32_t* __restrict__ base)
{
    __shared__ uint32_t part[256];
    int t = threadIdx.x;
    uint32_t local[16];
    uint32_t s = 0;
#pragma unroll
    for (int j = 0; j < 16; ++j) { local[j] = totals[t * 16 + j]; s += local[j]; }
    part[t] = s;
    __syncthreads();
    if (t == 0) {
        uint32_t run = 0;
        for (int i = 0; i < 256; ++i) { uint32_t tmp = part[i]; part[i] = run; run += tmp; }
    }
    __syncthreads();
    uint32_t run = part[t];
#pragma unroll
    for (int j = 0; j < 16; ++j) { base[t * 16 + j] = run; run += local[j]; }
    if (t == 255) base[NBINS] = run;
}

// ---- K3: scatter (cell_local, weight) pairs into bin-sorted order -----------
__global__ __launch_bounds__(BT) void k3_scatter(const float* __restrict__ pos,
                                                 const float* __restrict__ wgt,
                                                 const uint32_t* __restrict__ offs,
                                                 const uint32_t* __restrict__ base,
                                                 uint2* __restrict__ pairs,
                                                 int n)
{
    __shared__ uint32_t cur[NBINS];
    for (int i = threadIdx.x; i < NBINS; i += BT)
        cur[i] = base[i] + offs[(size_t)blockIdx.x * NBINS + i];
    __syncthreads();

    const float4* p4 = (const float4*)pos;
    const float4* w4 = (const float4*)wgt;
    int ngroups = n >> 2;
    int G = gridDim.x * BT;
    for (int g = blockIdx.x * BT + threadIdx.x; g < ngroups; g += G) {
        float4 a = p4[(size_t)g * 3 + 0];
        float4 b = p4[(size_t)g * 3 + 1];
        float4 c = p4[(size_t)g * 3 + 2];
        float4 w = w4[g];
        int   f[4]  = { particle_flat(a.x, a.y, a.z), particle_flat(a.w, b.x, b.y),
                        particle_flat(b.z, b.w, c.x), particle_flat(c.y, c.z, c.w) };
        float ww[4] = { w.x, w.y, w.z, w.w };
#pragma unroll
        for (int k = 0; k < 4; ++k) {
            if (f[k] >= 0) {
                uint32_t slot = atomicAdd(&cur[f[k] >> 12], 1u);
                pairs[slot] = make_uint2((uint32_t)(f[k] & 4095), __float_as_uint(ww[k]));
            }
        }
    }
    if (blockIdx.x == 0 && threadIdx.x == 0) {
        for (int p = n & ~3; p < n; ++p) {
            int f = particle_flat(pos[3 * p], pos[3 * p + 1], pos[3 * p + 2]);
            if (f >= 0) {
                uint32_t slot = atomicAdd(&cur[f >> 12], 1u);
                pairs[slot] = make_uint2((uint32_t)(f & 4095), __float_as_uint(wgt[p]));
            }
        }
    }
}

// ---- K4: one block per bin — LDS accumulate, plain coalesced store ----------
__global__ __launch_bounds__(BT) void k4_accum(const uint2* __restrict__ pairs,
                                               const uint32_t* __restrict__ base,
                                               float* __restrict__ grid)
{
    __shared__ float acc[NBINS];
    for (int i = threadIdx.x; i < NBINS; i += BT) acc[i] = 0.0f;
    __syncthreads();

    int b = blockIdx.x;
    uint32_t s = base[b], e = base[b + 1];
    for (uint32_t i = s + threadIdx.x; i < e; i += BT) {
        uint2 p = pairs[i];
        atomicAdd(&acc[p.x], __uint_as_float(p.y));
    }
    __syncthreads();

    float4* out4 = (float4*)(grid + (size_t)b * NBINS);
    const float4* a4 = (const float4*)acc;
    for (int i = threadIdx.x; i < NBINS / 4; i += BT) out4[i] = a4[i];
}

// ---- fallback: round-3 single-pass global-atomic kernel ---------------------
__global__ __launch_bounds__(BT) void forcegrid_scatter_atomic(
    const float* __restrict__ pos, const float* __restrict__ wgt,
    float* __restrict__ grid, int n)
{
    int t = blockIdx.x * blockDim.x + threadIdx.x;
    long long bse = (long long)t * 4;
    if (bse >= n) return;
    const float4* p4 = (const float4*)pos;
    float4 a = p4[(size_t)t * 3 + 0];
    float4 b = p4[(size_t)t * 3 + 1];
    float4 c = p4[(size_t)t * 3 + 2];
    float4 w = ((const float4*)wgt)[t];
    int   f[4]  = { particle_flat(a.x, a.y, a.z), particle_flat(a.w, b.x, b.y),
                    particle_flat(b.z, b.w, c.x), particle_flat(c.y, c.z, c.w) };
    float ww[4] = { w.x, w.y, w.z, w.w };
#pragma unroll
    for (int k = 0; k < 4; ++k) {
        if (bse + k >= n) break;
        if (f[k] >= 0) atomicAdd(&grid[f[k]], ww[k]);
    }
}

extern "C" void kernel_launch(void* const* d_in, const int* in_sizes, int n_in,
                              void* d_out, int out_size, void* d_ws, size_t ws_size,
                              hipStream_t stream)
{
    const float* pos = (const float*)d_in[0];   // [N,3]
    const float* wgt = (const float*)d_in[1];   // [N]
    float* grid = (float*)d_out;                // [256^3]
    int n = in_sizes[0] / 3;                    // 10,000,000

    // workspace carve
    size_t off = 0;
    uint2*    pairs  = (uint2*)d_ws;                         off += (size_t)n * sizeof(uint2);
    uint32_t* hist   = (uint32_t*)((char*)d_ws + off);       off += (size_t)NB * NBINS * 4;
    uint32_t* offs   = (uint32_t*)((char*)d_ws + off);       off += (size_t)NB * NBINS * 4;
    uint32_t* totals = (uint32_t*)((char*)d_ws + off);       off += (size_t)NBINS * 4;
    uint32_t* base   = (uint32_t*)((char*)d_ws + off);       off += (size_t)(NBINS + 1) * 4;

    if (ws_size >= off) {
        k1_hist   <<<NB,   BT,  0, stream>>>(pos, hist, n);
        k2a_colscan<<<NBINS / 128, 128, 0, stream>>>(hist, offs, totals);
        k2b_scan  <<<1,    256, 0, stream>>>(totals, base);
        k3_scatter<<<NB,   BT,  0, stream>>>(pos, wgt, offs, base, pairs, n);
        k4_accum  <<<NBINS, BT, 0, stream>>>(pairs, base, grid);
    } else {
        // workspace too small: single-pass atomic fallback (needs zeroed grid)
        hipMemsetAsync(grid, 0, (size_t)out_size * sizeof(float), stream);
        int groups = (n + 3) / 4;
        forcegrid_scatter_atomic<<<(groups + BT - 1) / BT, BT, 0, stream>>>(pos, wgt, grid, n);
    }
}

// Round 5
// 427.901 us; speedup vs baseline: 1.2554x; 1.0614x over previous
//
#include <hip/hip_runtime.h>
#include <stdint.h>

// ForceGrid: 10M weighted particles -> 256^3 float grid.
//
// Pipeline (no global atomics): counting-sort by 4096 bins (bin = flat>>12,
// 4096 cells = 16KB LDS), then per-bin LDS accumulation + coalesced stores.
// Round-4 counters: K3 scatter was the wall at 183us with Occupancy=20%
// (512 blocks x 256 thr = 8/32 waves per CU) — latency-bound on scattered
// 8B pair stores. Fix: 1024-thread blocks for K1/K3 (same 512-segment
// partition), and ILP for the K2a column scan.
//
// Numerics (bit-exact vs the XLA-folded reference; DO NOT change):
//   fi = fl32((p + 10.0f) * 12.75f)   // 12.75f == fl32(1/fl32(20/255))
//   i  = (int32)fl32(fi + 0.5f)       // trunc toward zero, NO FMA contraction

constexpr int GRID_N = 256;
constexpr int NBINS  = 4096;   // bin = flat >> 12 ; cell_local = flat & 4095
constexpr int NB     = 512;    // segments (= blocks) for hist/scatter passes
constexpr int BT13   = 1024;   // threads per block, K1/K3 (occupancy!)
constexpr int BT     = 256;    // threads per block, K4

__device__ __forceinline__ int particle_flat(float px, float py, float pz) {
#pragma clang fp contract(off)
    float fix = (px + 10.0f) * 12.75f;
    float fiy = (py + 10.0f) * 12.75f;
    float fiz = (pz + 10.0f) * 12.75f;
    int ix = (int)(fix + 0.5f);
    int iy = (int)(fiy + 0.5f);
    int iz = (int)(fiz + 0.5f);
    bool in = (ix >= 0) & (ix < GRID_N) &
              (iy >= 0) & (iy < GRID_N) &
              (iz >= 0) & (iz < GRID_N);
    return in ? ((ix << 16) | (iy << 8) | iz) : -1;
}

// ---- K1: per-block bin histogram (LDS atomics), hist[NB][NBINS] -------------
__global__ __launch_bounds__(BT13) void k1_hist(const float* __restrict__ pos,
                                                uint32_t* __restrict__ hist,
                                                int n)
{
    __shared__ uint32_t h[NBINS];
    for (int i = threadIdx.x; i < NBINS; i += BT13) h[i] = 0;
    __syncthreads();

    const float4* p4 = (const float4*)pos;
    int ngroups = n >> 2;
    int G = gridDim.x * BT13;
    for (int g = blockIdx.x * BT13 + threadIdx.x; g < ngroups; g += G) {
        float4 a = p4[(size_t)g * 3 + 0];
        float4 b = p4[(size_t)g * 3 + 1];
        float4 c = p4[(size_t)g * 3 + 2];
        int f0 = particle_flat(a.x, a.y, a.z);
        int f1 = particle_flat(a.w, b.x, b.y);
        int f2 = particle_flat(b.z, b.w, c.x);
        int f3 = particle_flat(c.y, c.z, c.w);
        if (f0 >= 0) atomicAdd(&h[f0 >> 12], 1u);
        if (f1 >= 0) atomicAdd(&h[f1 >> 12], 1u);
        if (f2 >= 0) atomicAdd(&h[f2 >> 12], 1u);
        if (f3 >= 0) atomicAdd(&h[f3 >> 12], 1u);
    }
    // tail (n % 4) particles, counted by block 0 only
    if (blockIdx.x == 0 && threadIdx.x == 0) {
        for (int p = n & ~3; p < n; ++p) {
            int f = particle_flat(pos[3 * p], pos[3 * p + 1], pos[3 * p + 2]);
            if (f >= 0) atomicAdd(&h[f >> 12], 1u);
        }
    }
    __syncthreads();
    uint32_t* out = hist + (size_t)blockIdx.x * NBINS;
    for (int i = threadIdx.x; i < NBINS; i += BT13) out[i] = h[i];
}

// ---- K2a: per-bin scan across blocks (coalesced, unroll-8 for ILP) ----------
__global__ __launch_bounds__(128) void k2a_colscan(const uint32_t* __restrict__ hist,
                                                   uint32_t* __restrict__ offs,
                                                   uint32_t* __restrict__ totals)
{
    int b = blockIdx.x * 128 + threadIdx.x;   // 32 blocks x 128 = 4096 bins
    uint32_t run = 0;
    for (int blk = 0; blk < NB; blk += 8) {
        uint32_t v[8];
#pragma unroll
        for (int j = 0; j < 8; ++j)
            v[j] = hist[(size_t)(blk + j) * NBINS + b];   // 8 independent loads
#pragma unroll
        for (int j = 0; j < 8; ++j) {
            offs[(size_t)(blk + j) * NBINS + b] = run;
            run += v[j];
        }
    }
    totals[b] = run;
}

// ---- K2b: exclusive scan of 4096 bin totals -> base[NBINS+1] ----------------
__global__ __launch_bounds__(256) void k2b_scan(const uint32_t* __restrict__ totals,
                                                uint32_t* __restrict__ base)
{
    __shared__ uint32_t part[256];
    int t = threadIdx.x;
    uint32_t local[16];
    uint32_t s = 0;
#pragma unroll
    for (int j = 0; j < 16; ++j) { local[j] = totals[t * 16 + j]; s += local[j]; }
    part[t] = s;
    __syncthreads();
    if (t == 0) {
        uint32_t run = 0;
        for (int i = 0; i < 256; ++i) { uint32_t tmp = part[i]; part[i] = run; run += tmp; }
    }
    __syncthreads();
    uint32_t run = part[t];
#pragma unroll
    for (int j = 0; j < 16; ++j) { base[t * 16 + j] = run; run += local[j]; }
    if (t == 255) base[NBINS] = run;
}

// ---- K3: scatter (cell_local, weight) pairs into bin-sorted order -----------
__global__ __launch_bounds__(BT13) void k3_scatter(const float* __restrict__ pos,
                                                   const float* __restrict__ wgt,
                                                   const uint32_t* __restrict__ offs,
                                                   const uint32_t* __restrict__ base,
                                                   uint2* __restrict__ pairs,
                                                   int n)
{
    __shared__ uint32_t cur[NBINS];
    for (int i = threadIdx.x; i < NBINS; i += BT13)
        cur[i] = base[i] + offs[(size_t)blockIdx.x * NBINS + i];
    __syncthreads();

    const float4* p4 = (const float4*)pos;
    const float4* w4 = (const float4*)wgt;
    int ngroups = n >> 2;
    int G = gridDim.x * BT13;
    for (int g = blockIdx.x * BT13 + threadIdx.x; g < ngroups; g += G) {
        float4 a = p4[(size_t)g * 3 + 0];
        float4 b = p4[(size_t)g * 3 + 1];
        float4 c = p4[(size_t)g * 3 + 2];
        float4 w = w4[g];
        int   f[4]  = { particle_flat(a.x, a.y, a.z), particle_flat(a.w, b.x, b.y),
                        particle_flat(b.z, b.w, c.x), particle_flat(c.y, c.z, c.w) };
        float ww[4] = { w.x, w.y, w.z, w.w };
#pragma unroll
        for (int k = 0; k < 4; ++k) {
            if (f[k] >= 0) {
                uint32_t slot = atomicAdd(&cur[f[k] >> 12], 1u);
                pairs[slot] = make_uint2((uint32_t)(f[k] & 4095), __float_as_uint(ww[k]));
            }
        }
    }
    if (blockIdx.x == 0 && threadIdx.x == 0) {
        for (int p = n & ~3; p < n; ++p) {
            int f = particle_flat(pos[3 * p], pos[3 * p + 1], pos[3 * p + 2]);
            if (f >= 0) {
                uint32_t slot = atomicAdd(&cur[f >> 12], 1u);
                pairs[slot] = make_uint2((uint32_t)(f & 4095), __float_as_uint(wgt[p]));
            }
        }
    }
}

// ---- K4: one block per bin — LDS accumulate, plain coalesced store ----------
__global__ __launch_bounds__(BT) void k4_accum(const uint2* __restrict__ pairs,
                                               const uint32_t* __restrict__ base,
                                               float* __restrict__ grid)
{
    __shared__ float acc[NBINS];
    for (int i = threadIdx.x; i < NBINS; i += BT) acc[i] = 0.0f;
    __syncthreads();

    int b = blockIdx.x;
    uint32_t s = base[b], e = base[b + 1];
    for (uint32_t i = s + threadIdx.x; i < e; i += BT) {
        uint2 p = pairs[i];
        atomicAdd(&acc[p.x], __uint_as_float(p.y));
    }
    __syncthreads();

    float4* out4 = (float4*)(grid + (size_t)b * NBINS);
    const float4* a4 = (const float4*)acc;
    for (int i = threadIdx.x; i < NBINS / 4; i += BT) out4[i] = a4[i];
}

// ---- fallback: single-pass global-atomic kernel -----------------------------
__global__ __launch_bounds__(BT) void forcegrid_scatter_atomic(
    const float* __restrict__ pos, const float* __restrict__ wgt,
    float* __restrict__ grid, int n)
{
    int t = blockIdx.x * blockDim.x + threadIdx.x;
    long long bse = (long long)t * 4;
    if (bse >= n) return;
    const float4* p4 = (const float4*)pos;
    float4 a = p4[(size_t)t * 3 + 0];
    float4 b = p4[(size_t)t * 3 + 1];
    float4 c = p4[(size_t)t * 3 + 2];
    float4 w = ((const float4*)wgt)[t];
    int   f[4]  = { particle_flat(a.x, a.y, a.z), particle_flat(a.w, b.x, b.y),
                    particle_flat(b.z, b.w, c.x), particle_flat(c.y, c.z, c.w) };
    float ww[4] = { w.x, w.y, w.z, w.w };
#pragma unroll
    for (int k = 0; k < 4; ++k) {
        if (bse + k >= n) break;
        if (f[k] >= 0) atomicAdd(&grid[f[k]], ww[k]);
    }
}

extern "C" void kernel_launch(void* const* d_in, const int* in_sizes, int n_in,
                              void* d_out, int out_size, void* d_ws, size_t ws_size,
                              hipStream_t stream)
{
    const float* pos = (const float*)d_in[0];   // [N,3]
    const float* wgt = (const float*)d_in[1];   // [N]
    float* grid = (float*)d_out;                // [256^3]
    int n = in_sizes[0] / 3;                    // 10,000,000

    // workspace carve (identical layout/size to round 4 — known to fit)
    size_t off = 0;
    uint2*    pairs  = (uint2*)d_ws;                         off += (size_t)n * sizeof(uint2);
    uint32_t* hist   = (uint32_t*)((char*)d_ws + off);       off += (size_t)NB * NBINS * 4;
    uint32_t* offs   = (uint32_t*)((char*)d_ws + off);       off += (size_t)NB * NBINS * 4;
    uint32_t* totals = (uint32_t*)((char*)d_ws + off);       off += (size_t)NBINS * 4;
    uint32_t* base   = (uint32_t*)((char*)d_ws + off);       off += (size_t)(NBINS + 1) * 4;

    if (ws_size >= off) {
        k1_hist    <<<NB,          BT13, 0, stream>>>(pos, hist, n);
        k2a_colscan<<<NBINS / 128, 128,  0, stream>>>(hist, offs, totals);
        k2b_scan   <<<1,           256,  0, stream>>>(totals, base);
        k3_scatter <<<NB,          BT13, 0, stream>>>(pos, wgt, offs, base, pairs, n);
        k4_accum   <<<NBINS,       BT,   0, stream>>>(pairs, base, grid);
    } else {
        // workspace too small: single-pass atomic fallback (needs zeroed grid)
        hipMemsetAsync(grid, 0, (size_t)out_size * sizeof(float), stream);
        int groups = (n + 3) / 4;
        forcegrid_scatter_atomic<<<(groups + BT - 1) / BT, BT, 0, stream>>>(pos, wgt, grid, n);
    }
}

// Round 6
// 382.742 us; speedup vs baseline: 1.4036x; 1.1180x over previous
//
#include <hip/hip_runtime.h>
#include <stdint.h>

// ForceGrid: 10M weighted particles -> 256^3 float grid.
//
// Pipeline (no global atomics): counting-sort by SB=1024 superbins
// (superbin = flat>>14 = 16384 cells = 64KB LDS in K4), then per-superbin
// LDS accumulation + coalesced stores.
//
// Round-5 finding: K3's wall is write-sector amplification (WRITE_SIZE
// 227MB for 60MB of pairs, identical across occupancy changes). Cause:
// open 64B tail lines per (resident block, bin) = 64 blk/XCD x 4096 bins
// x 64B = 16MB >> 4MB per-XCD L2 -> partial-line writebacks. Fix: SB=1024
// bins, NB=256 blocks -> 32 blk/XCD x 1024 x 64B = 2MB, fits L2, lines
// fill before eviction.
//
// Numerics (bit-exact vs the XLA-folded reference; DO NOT change):
//   fi = fl32((p + 10.0f) * 12.75f)   // 12.75f == fl32(1/fl32(20/255))
//   i  = (int32)fl32(fi + 0.5f)       // trunc toward zero, NO FMA contraction

constexpr int GRID_N = 256;
constexpr int SB     = 1024;    // superbins; superbin = flat >> 14
constexpr int CELLS  = 16384;   // cells per superbin (64KB LDS in K4)
constexpr int NB     = 256;     // segments (= blocks) for hist/scatter passes
constexpr int BT13   = 1024;    // threads per block, K1/K3/K4

__device__ __forceinline__ int particle_flat(float px, float py, float pz) {
#pragma clang fp contract(off)
    float fix = (px + 10.0f) * 12.75f;
    float fiy = (py + 10.0f) * 12.75f;
    float fiz = (pz + 10.0f) * 12.75f;
    int ix = (int)(fix + 0.5f);
    int iy = (int)(fiy + 0.5f);
    int iz = (int)(fiz + 0.5f);
    bool in = (ix >= 0) & (ix < GRID_N) &
              (iy >= 0) & (iy < GRID_N) &
              (iz >= 0) & (iz < GRID_N);
    return in ? ((ix << 16) | (iy << 8) | iz) : -1;
}

// ---- K1: per-block superbin histogram (LDS atomics), hist[NB][SB] -----------
__global__ __launch_bounds__(BT13) void k1_hist(const float* __restrict__ pos,
                                                uint32_t* __restrict__ hist,
                                                int n)
{
    __shared__ uint32_t h[SB];
    for (int i = threadIdx.x; i < SB; i += BT13) h[i] = 0;
    __syncthreads();

    const float4* p4 = (const float4*)pos;
    int ngroups = n >> 2;
    int G = gridDim.x * BT13;
    for (int g = blockIdx.x * BT13 + threadIdx.x; g < ngroups; g += G) {
        float4 a = p4[(size_t)g * 3 + 0];
        float4 b = p4[(size_t)g * 3 + 1];
        float4 c = p4[(size_t)g * 3 + 2];
        int f0 = particle_flat(a.x, a.y, a.z);
        int f1 = particle_flat(a.w, b.x, b.y);
        int f2 = particle_flat(b.z, b.w, c.x);
        int f3 = particle_flat(c.y, c.z, c.w);
        if (f0 >= 0) atomicAdd(&h[f0 >> 14], 1u);
        if (f1 >= 0) atomicAdd(&h[f1 >> 14], 1u);
        if (f2 >= 0) atomicAdd(&h[f2 >> 14], 1u);
        if (f3 >= 0) atomicAdd(&h[f3 >> 14], 1u);
    }
    // tail (n % 4) particles, counted by block 0 only
    if (blockIdx.x == 0 && threadIdx.x == 0) {
        for (int p = n & ~3; p < n; ++p) {
            int f = particle_flat(pos[3 * p], pos[3 * p + 1], pos[3 * p + 2]);
            if (f >= 0) atomicAdd(&h[f >> 14], 1u);
        }
    }
    __syncthreads();
    uint32_t* out = hist + (size_t)blockIdx.x * SB;
    for (int i = threadIdx.x; i < SB; i += BT13) out[i] = h[i];
}

// ---- K2a: per-bin scan across blocks (coalesced, unroll-8 for ILP) ----------
__global__ __launch_bounds__(128) void k2a_colscan(const uint32_t* __restrict__ hist,
                                                   uint32_t* __restrict__ offs,
                                                   uint32_t* __restrict__ totals)
{
    int b = blockIdx.x * 128 + threadIdx.x;   // 8 blocks x 128 = 1024 bins
    uint32_t run = 0;
    for (int blk = 0; blk < NB; blk += 8) {
        uint32_t v[8];
#pragma unroll
        for (int j = 0; j < 8; ++j)
            v[j] = hist[(size_t)(blk + j) * SB + b];   // 8 independent loads
#pragma unroll
        for (int j = 0; j < 8; ++j) {
            offs[(size_t)(blk + j) * SB + b] = run;
            run += v[j];
        }
    }
    totals[b] = run;
}

// ---- K2b: exclusive scan of 1024 bin totals -> base[SB+1] -------------------
__global__ __launch_bounds__(256) void k2b_scan(const uint32_t* __restrict__ totals,
                                                uint32_t* __restrict__ base)
{
    __shared__ uint32_t part[256];
    int t = threadIdx.x;
    uint32_t local[4];
    uint32_t s = 0;
#pragma unroll
    for (int j = 0; j < 4; ++j) { local[j] = totals[t * 4 + j]; s += local[j]; }
    part[t] = s;
    __syncthreads();
    if (t == 0) {
        uint32_t run = 0;
        for (int i = 0; i < 256; ++i) { uint32_t tmp = part[i]; part[i] = run; run += tmp; }
    }
    __syncthreads();
    uint32_t run = part[t];
#pragma unroll
    for (int j = 0; j < 4; ++j) { base[t * 4 + j] = run; run += local[j]; }
    if (t == 255) base[SB] = run;
}

// ---- K3: scatter (cell_local, weight) pairs into superbin-sorted order ------
__global__ __launch_bounds__(BT13) void k3_scatter(const float* __restrict__ pos,
                                                   const float* __restrict__ wgt,
                                                   const uint32_t* __restrict__ offs,
                                                   const uint32_t* __restrict__ base,
                                                   uint2* __restrict__ pairs,
                                                   int n)
{
    __shared__ uint32_t cur[SB];
    for (int i = threadIdx.x; i < SB; i += BT13)
        cur[i] = base[i] + offs[(size_t)blockIdx.x * SB + i];
    __syncthreads();

    const float4* p4 = (const float4*)pos;
    const float4* w4 = (const float4*)wgt;
    int ngroups = n >> 2;
    int G = gridDim.x * BT13;
    for (int g = blockIdx.x * BT13 + threadIdx.x; g < ngroups; g += G) {
        float4 a = p4[(size_t)g * 3 + 0];
        float4 b = p4[(size_t)g * 3 + 1];
        float4 c = p4[(size_t)g * 3 + 2];
        float4 w = w4[g];
        int   f[4]  = { particle_flat(a.x, a.y, a.z), particle_flat(a.w, b.x, b.y),
                        particle_flat(b.z, b.w, c.x), particle_flat(c.y, c.z, c.w) };
        float ww[4] = { w.x, w.y, w.z, w.w };
#pragma unroll
        for (int k = 0; k < 4; ++k) {
            if (f[k] >= 0) {
                uint32_t slot = atomicAdd(&cur[f[k] >> 14], 1u);
                pairs[slot] = make_uint2((uint32_t)(f[k] & (CELLS - 1)),
                                         __float_as_uint(ww[k]));
            }
        }
    }
    if (blockIdx.x == 0 && threadIdx.x == 0) {
        for (int p = n & ~3; p < n; ++p) {
            int f = particle_flat(pos[3 * p], pos[3 * p + 1], pos[3 * p + 2]);
            if (f >= 0) {
                uint32_t slot = atomicAdd(&cur[f >> 14], 1u);
                pairs[slot] = make_uint2((uint32_t)(f & (CELLS - 1)),
                                         __float_as_uint(wgt[p]));
            }
        }
    }
}

// ---- K4: one block per superbin — 64KB LDS accumulate, coalesced store ------
__global__ __launch_bounds__(BT13) void k4_accum(const uint2* __restrict__ pairs,
                                                 const uint32_t* __restrict__ base,
                                                 float* __restrict__ grid)
{
    __shared__ float acc[CELLS];   // 64KB — 2 blocks/CU
    for (int i = threadIdx.x; i < CELLS; i += BT13) acc[i] = 0.0f;
    __syncthreads();

    int b = blockIdx.x;
    uint32_t s = base[b], e = base[b + 1];
    for (uint32_t i = s + threadIdx.x; i < e; i += BT13) {
        uint2 p = pairs[i];
        atomicAdd(&acc[p.x], __uint_as_float(p.y));
    }
    __syncthreads();

    float4* out4 = (float4*)(grid + (size_t)b * CELLS);
    const float4* a4 = (const float4*)acc;
    for (int i = threadIdx.x; i < CELLS / 4; i += BT13) out4[i] = a4[i];
}

// ---- fallback: single-pass global-atomic kernel -----------------------------
__global__ __launch_bounds__(256) void forcegrid_scatter_atomic(
    const float* __restrict__ pos, const float* __restrict__ wgt,
    float* __restrict__ grid, int n)
{
    int t = blockIdx.x * blockDim.x + threadIdx.x;
    long long bse = (long long)t * 4;
    if (bse >= n) return;
    const float4* p4 = (const float4*)pos;
    float4 a = p4[(size_t)t * 3 + 0];
    float4 b = p4[(size_t)t * 3 + 1];
    float4 c = p4[(size_t)t * 3 + 2];
    float4 w = ((const float4*)wgt)[t];
    int   f[4]  = { particle_flat(a.x, a.y, a.z), particle_flat(a.w, b.x, b.y),
                    particle_flat(b.z, b.w, c.x), particle_flat(c.y, c.z, c.w) };
    float ww[4] = { w.x, w.y, w.z, w.w };
#pragma unroll
    for (int k = 0; k < 4; ++k) {
        if (bse + k >= n) break;
        if (f[k] >= 0) atomicAdd(&grid[f[k]], ww[k]);
    }
}

extern "C" void kernel_launch(void* const* d_in, const int* in_sizes, int n_in,
                              void* d_out, int out_size, void* d_ws, size_t ws_size,
                              hipStream_t stream)
{
    const float* pos = (const float*)d_in[0];   // [N,3]
    const float* wgt = (const float*)d_in[1];   // [N]
    float* grid = (float*)d_out;                // [256^3]
    int n = in_sizes[0] / 3;                    // 10,000,000

    // workspace carve (~82 MB)
    size_t off = 0;
    uint2*    pairs  = (uint2*)d_ws;                         off += (size_t)n * sizeof(uint2);
    uint32_t* hist   = (uint32_t*)((char*)d_ws + off);       off += (size_t)NB * SB * 4;
    uint32_t* offs   = (uint32_t*)((char*)d_ws + off);       off += (size_t)NB * SB * 4;
    uint32_t* totals = (uint32_t*)((char*)d_ws + off);       off += (size_t)SB * 4;
    uint32_t* base   = (uint32_t*)((char*)d_ws + off);       off += (size_t)(SB + 1) * 4;

    if (ws_size >= off) {
        k1_hist    <<<NB,       BT13, 0, stream>>>(pos, hist, n);
        k2a_colscan<<<SB / 128, 128,  0, stream>>>(hist, offs, totals);
        k2b_scan   <<<1,        256,  0, stream>>>(totals, base);
        k3_scatter <<<NB,       BT13, 0, stream>>>(pos, wgt, offs, base, pairs, n);
        k4_accum   <<<SB,       BT13, 0, stream>>>(pairs, base, grid);
    } else {
        // workspace too small: single-pass atomic fallback (needs zeroed grid)
        hipMemsetAsync(grid, 0, (size_t)out_size * sizeof(float), stream);
        int groups = (n + 3) / 4;
        forcegrid_scatter_atomic<<<(groups + 255) / 256, 256, 0, stream>>>(pos, wgt, grid, n);
    }
}